// Round 10
// baseline (354.619 us; speedup 1.0000x reference)
//
#include <hip/hip_runtime.h>
#include <cstdint>
#include <cstddef>

// Problem constants (B,S,E,H)=(2,2048,2048,16), D=128, RD=128 (full-rotary)
#define Bd 2
#define Sd 2048
#define Ed 2048
#define Hd 16
#define Dd 128
#define N3E 6144
#define ATT_SCALE 0.08838834764831845f   // 1/sqrt(128)
#define C2LOG 0.12751743f                // ATT_SCALE * log2(e): softmax in 2^x domain

typedef short bf16x8 __attribute__((ext_vector_type(8)));
typedef float f32x4 __attribute__((ext_vector_type(4)));
typedef float f32x16 __attribute__((ext_vector_type(16)));

__device__ __forceinline__ float bf2f(unsigned short u) {
    union { unsigned int u; float f; } c;
    c.u = ((unsigned int)u) << 16;
    return c.f;
}
__device__ __forceinline__ unsigned short f2bf(float f) {
    union { float f; unsigned int u; } c;
    c.f = f;
    unsigned int x = c.u;
    x += 0x7FFFu + ((x >> 16) & 1u);   // RTNE (finite values only)
    return (unsigned short)(x >> 16);
}

// raw v_exp_f32 = 2^x
__device__ __forceinline__ float exp2_fast(float x) {
    float r;
    asm("v_exp_f32 %0, %1" : "=v"(r) : "v"(x));
    return r;
}
// pack 2 f32 -> 2 bf16 (RTNE), lo in low half (T12 primitive; no builtin)
__device__ __forceinline__ unsigned int cvtpk_bf16(float lo, float hi) {
    unsigned int r;
    asm("v_cvt_pk_bf16_f32 %0, %1, %2" : "=v"(r) : "v"(lo), "v"(hi));
    return r;
}

__device__ __forceinline__ void gl2lds16(const void* g, void* l) {
    __builtin_amdgcn_global_load_lds(
        (const __attribute__((address_space(1))) void*)g,
        (__attribute__((address_space(3))) void*)l, 16, 0, 0);
}

// ---------------- fp32 -> bf16 convert (x, wqkv_w, out_w in one launch) ----
// 8 elems/thread, 2x float4 loads -> 1x uint4 store (v_cvt_pk packs).
__global__ void cvt_all(const float* __restrict__ x,
                        const float* __restrict__ w1,
                        const float* __restrict__ w2,
                        unsigned short* __restrict__ ox,
                        unsigned short* __restrict__ o1,
                        unsigned short* __restrict__ o2) {
    int i = (blockIdx.x * 256 + threadIdx.x) * 8;
    const float* s;
    unsigned short* d;
    int off;
    if (i < 8388608) { s = x; d = ox; off = i; }
    else if (i < 20971520) { s = w1; d = o1; off = i - 8388608; }
    else { s = w2; d = o2; off = i - 20971520; }
    const float4 v0 = *(const float4*)(s + off);
    const float4 v1 = *(const float4*)(s + off + 4);
    uint4 w;
    w.x = cvtpk_bf16(v0.x, v0.y);
    w.y = cvtpk_bf16(v0.z, v0.w);
    w.z = cvtpk_bf16(v1.x, v1.y);
    w.w = cvtpk_bf16(v1.z, v1.w);
    *(uint4*)(d + off) = w;
}

// ---------------- bf16 MFMA GEMM, C = A * B^T + bias ----------------
// (proven 927-TF structure: 128x128 tile, BK=64, 4 waves, 33 KB LDS ->
//  4 blocks/CU; inter-block overlap hides the per-tile drain. R10: QKV
//  back to ONE (48,32) dispatch -- the R7-R9 two-half split served its
//  diagnostic purpose (flash measured at 74.4 us) but runs at 3 blocks/CU
//  with an extra tail; single dispatch measured 107-108 us.)
// A: M x K (K contig), Bm: N x K (K contig). XOR-swizzled LDS (8 chunks/row
// of 16B) so frag ds_read_b128 is 2-way (free).
// MODE 0: fp32 row-major out (o0), Ndim cols.
// MODE 1: fused QKV epilogue. Each 128-col tile = one head (D=128) of q/k/v:
//   tile -> LDS (bf16, stride 130), then q/k: RoPE + store [B,H,S,D];
//   v: transpose via column gather -> [B,H,D,S].
template <int MODE>
__global__ void gemm_bt(const unsigned short* __restrict__ A,
                        const unsigned short* __restrict__ Bm,
                        const float* __restrict__ bias,
                        void* __restrict__ o0, void* __restrict__ o1,
                        void* __restrict__ o2, int Ndim, int K, int moff) {
    // union: staging (As 16KB + Bs 16KB) / epilogue tile 128x130 bf16 (33,280B)
    __shared__ __align__(16) unsigned short U[16640];
    unsigned short* As = U;
    unsigned short* Bs = U + 8192;

    const int tid = threadIdx.x;
    const int lane = tid & 63;
    const int wave = tid >> 6;
    const int quad = lane >> 4;
    const int l16 = lane & 15;
    const int wr = wave >> 1;
    const int wc = wave & 1;

    const int n0 = blockIdx.x * 128;
    const int m0 = blockIdx.y * 128 + moff;

    const unsigned short* Ab = A + (size_t)m0 * K;
    const unsigned short* Bb = Bm + (size_t)n0 * K;

    const f32x4 fzero = {0.f, 0.f, 0.f, 0.f};
    f32x4 acc[4][4];
#pragma unroll
    for (int i = 0; i < 4; i++)
#pragma unroll
        for (int j = 0; j < 4; j++) acc[i][j] = fzero;

    for (int k0 = 0; k0 < K; k0 += 64) {
        __syncthreads();
#pragma unroll
        for (int it = 0; it < 4; ++it) {
            int L = it * 256 + tid;
            int row = L >> 3;
            int cs = L & 7;
            int gc = cs ^ (row & 7);
            gl2lds16(Ab + row * K + k0 + gc * 8, (void*)(As + L * 8));
            gl2lds16(Bb + row * K + k0 + gc * 8, (void*)(Bs + L * 8));
        }
        __syncthreads();
#pragma unroll
        for (int kk = 0; kk < 2; ++kk) {
            bf16x8 af[4], bfr[4];
#pragma unroll
            for (int i = 0; i < 4; i++) {
                int row = wr * 64 + i * 16 + l16;
                int cs = kk * 4 + quad;
                af[i] = *(const bf16x8*)(As + row * 64 + (cs ^ (row & 7)) * 8);
            }
#pragma unroll
            for (int j = 0; j < 4; j++) {
                int row = wc * 64 + j * 16 + l16;
                int cs = kk * 4 + quad;
                bfr[j] = *(const bf16x8*)(Bs + row * 64 + (cs ^ (row & 7)) * 8);
            }
#pragma unroll
            for (int i = 0; i < 4; i++)
#pragma unroll
                for (int j = 0; j < 4; j++)
                    acc[i][j] = __builtin_amdgcn_mfma_f32_16x16x32_bf16(
                        af[i], bfr[j], acc[i][j], 0, 0, 0);
        }
    }

    if (MODE == 0) {
#pragma unroll
        for (int j = 0; j < 4; j++) {
            int col = n0 + wc * 64 + j * 16 + l16;
            float bv = bias[col];
#pragma unroll
            for (int i = 0; i < 4; i++) {
                int rbase = m0 + wr * 64 + i * 16 + quad * 4;
#pragma unroll
                for (int r = 0; r < 4; r++)
                    ((float*)o0)[(size_t)(rbase + r) * Ndim + col] =
                        acc[i][j][r] + bv;
            }
        }
    } else {
        // ---- fused QKV epilogue ----
        __syncthreads();  // all frag reads of As/Bs done before tile overwrite
#pragma unroll
        for (int j = 0; j < 4; j++) {
            int coll = wc * 64 + j * 16 + l16;   // tile-local col = d
            float bv = bias[n0 + coll];
#pragma unroll
            for (int i = 0; i < 4; i++) {
                int rl = wr * 64 + i * 16 + quad * 4;
#pragma unroll
                for (int r = 0; r < 4; r++)
                    U[(rl + r) * 130 + coll] = f2bf(acc[i][j][r] + bv);
            }
        }
        __syncthreads();

        const int ch = n0 >> 7;         // 0..47
        const int c = ch >> 4;          // 0=q 1=k 2=v
        const int h = ch & 15;
        const int bb = m0 >> 11;        // batch (tile never crosses: 2048%128==0)
        const int s0 = m0 & 2047;

        if (c < 2) {
            unsigned short* dstq = (unsigned short*)(c == 0 ? o0 : o1);
            const size_t hb = ((size_t)(bb * Hd + h)) * Sd;
#pragma unroll
            for (int it = 0; it < 16; ++it) {
                int lin = it * 256 + tid;        // 128 rows x 32 d-pairs
                int row = lin >> 5, p = lin & 31;
                int s = s0 + row;
                unsigned int lo = *(const unsigned int*)(U + row * 130 + 2 * p);
                unsigned int hi =
                    *(const unsigned int*)(U + row * 130 + 64 + 2 * p);
                float v1a = bf2f((unsigned short)lo), v1b = bf2f(lo >> 16);
                float v2a = bf2f((unsigned short)hi), v2b = bf2f(hi >> 16);
                // theta_j = s * 10000^(-j/64),  j = 2p, 2p+1
                float fa = (float)s * __expf(-(float)(2 * p) *
                                             (9.210340371976184f / 64.0f));
                float fb = (float)s * __expf(-(float)(2 * p + 1) *
                                             (9.210340371976184f / 64.0f));
                float sna, csa, snb, csb;
                __sincosf(fa, &sna, &csa);
                __sincosf(fb, &snb, &csb);
                ushort2 r1, r2;
                r1.x = f2bf(v1a * csa - v2a * sna);
                r1.y = f2bf(v1b * csb - v2b * snb);
                r2.x = f2bf(v1a * sna + v2a * csa);
                r2.y = f2bf(v1b * snb + v2b * csb);
                unsigned short* dst = dstq + (hb + s) * Dd;
                *(ushort2*)(dst + 2 * p) = r1;
                *(ushort2*)(dst + 64 + 2 * p) = r2;
            }
        } else {
            unsigned short* dstv = (unsigned short*)o2;
            const size_t hb = ((size_t)(bb * Hd + h)) * Dd;
#pragma unroll
            for (int it = 0; it < 16; ++it) {
                int lin = it * 256 + tid;        // 128 d x 32 s-chunks
                int d = lin >> 5, sc = lin & 31;
                int s4 = sc * 4;
                ushort4 pk;
                pk.x = U[(s4 + 0) * 130 + d];
                pk.y = U[(s4 + 1) * 130 + d];
                pk.z = U[(s4 + 2) * 130 + d];
                pk.w = U[(s4 + 3) * 130 + d];
                *(ushort4*)(dstv + (hb + d) * Sd + s0 + s4) = pk;
            }
        }
    }
}

// ---------------- flash attention (causal, online softmax) ----------------
// FOLDED uniform schedule (measured R9: 74.4 us, MfmaUtil 18.5%, frozen this
// round). Grid (32 bh x 8), each block processes TWO q-tiles sequentially --
// qi = 15-y (long) then qi = y (short) -- 34 iters for every block; 256
// blocks = 1/CU. Per-tile body: double-buffered K/V stage-early (one
// sync/tile), in-register P via cvt_pk + v_permlane32_swap_b32 (no Ps LDS),
// log2-domain softmax, defer-max (T13), diagonal skips.
// Buffer parity: pass 0 flips `cur` an even number of times (2*qi+2), so
// cur==0 at pass-1 entry, matching stage(0,0).
// 32x32 layouts (verified m74/m101): A/B [n=lane&31][k=(lane>>5)*8+j];
// C/D col=lane&31, row=(reg&3)+8*(reg>>2)+4*(lane>>5).
__global__ __launch_bounds__(256, 2) void flash_attn(
    const unsigned short* __restrict__ q, const unsigned short* __restrict__ k,
    const unsigned short* __restrict__ vt, unsigned short* __restrict__ ctx) {
    __shared__ __align__(16) unsigned short Ks[2][64 * 128];   // 2x16 KB [t][d], 16 chunks/row, xor row&15
    __shared__ __align__(16) unsigned short Vts[2][128 * 64];  // 2x16 KB [d][t], 8 chunks/row, xor row&7

    const int tid = threadIdx.x;
    const int lane = tid & 63;
    const int wave = tid >> 6;
    const int l32 = lane & 31;
    const int half = lane >> 5;

    const int bh = blockIdx.x;
    const int yp = blockIdx.y;          // 0..7

    const unsigned short* kb = k + (size_t)bh * Sd * Dd;
    const unsigned short* vtb = vt + (size_t)bh * Dd * Sd;
    const int b = bh >> 4;
    const int h = bh & 15;

    // stage K [64t][128d] and Vt [128d][64t] into buffer bb, 1024 16B-chunks each
    auto stage = [&](int bb2, int t0) {
#pragma unroll
        for (int it = 0; it < 4; ++it) {
            int L = it * 256 + tid;
            int rk = L >> 4;
            int ck = L & 15;
            int gk = ck ^ (rk & 15);
            gl2lds16(kb + (size_t)(t0 + rk) * Dd + gk * 8,
                     (void*)(&Ks[bb2][0] + L * 8));
            int rv = L >> 3;
            int cv = L & 7;
            int gv = cv ^ (rv & 7);
            gl2lds16(vtb + (size_t)rv * Sd + t0 + gv * 8,
                     (void*)(&Vts[bb2][0] + L * 8));
        }
    };

    for (int pass = 0; pass < 2; ++pass) {
        const int qi = (pass == 0) ? (15 - yp) : yp;
        const int q0 = qi * 128;
        const int qg = q0 + wave * 32 + l32;    // this lane's global q row

        // Q fragments straight from global: lane owns row qg, frag ks covers
        // d = ks*16 + half*8 + {0..7}  (B-operand layout), 8 x 16B loads.
        bf16x8 aq[8];
        {
            const unsigned short* qrow = q + ((size_t)bh * Sd + qg) * Dd;
#pragma unroll
            for (int ks = 0; ks < 8; ks++)
                aq[ks] = *(const bf16x8*)(qrow + ks * 16 + half * 8);
        }

        f32x16 o[4];   // O^T: row d = db*32+(r&3)+8*(r>>2)+4*half, col q=l32
#pragma unroll
        for (int db = 0; db < 4; db++)
#pragma unroll
            for (int r = 0; r < 16; r++) o[db][r] = 0.f;
        float mi = -3.0e38f, li = 0.f;

        const int tmax = q0 + 64;
        if (pass) __syncthreads();   // pass-0's last-tile reads done
        stage(0, 0);
        int cur = 0;
        for (int t0 = 0; t0 <= tmax; t0 += 64) {
            __syncthreads();   // buf[cur] landed; prev iter's buf[cur^1] reads done
            if (t0 + 64 <= tmax) stage(cur ^ 1, t0 + 64);

            // waves entirely above the diagonal have nothing to do this tile
            if (t0 <= q0 + wave * 32 + 31) {
                const unsigned short* Ksc = &Ks[cur][0];
                const unsigned short* Vtsc = &Vts[cur][0];

                // S^T = K * Q^T : 2 t-blocks of 32, contraction d=128 (8 ksteps)
                f32x16 sa[2];
#pragma unroll
                for (int b2 = 0; b2 < 2; b2++)
#pragma unroll
                    for (int r = 0; r < 16; r++) sa[b2][r] = 0.f;
#pragma unroll
                for (int ks = 0; ks < 8; ks++) {
                    int cd = ks * 2 + half;
#pragma unroll
                    for (int b2 = 0; b2 < 2; b2++) {
                        int row = b2 * 32 + l32;
                        bf16x8 ak = *(const bf16x8*)(Ksc + row * 128 +
                                                     (cd ^ (row & 15)) * 8);
                        sa[b2] = __builtin_amdgcn_mfma_f32_32x32x16_bf16(
                            ak, aq[ks], sa[b2], 0, 0, 0);
                    }
                }

                // scale into log2 domain; mask only if wave straddles diagonal
                float mx = -3.0e38f;
                if (t0 + 63 > q0 + wave * 32) {   // wave-uniform
#pragma unroll
                    for (int b2 = 0; b2 < 2; b2++)
#pragma unroll
                        for (int r = 0; r < 16; r++) {
                            float v = sa[b2][r] * C2LOG;
                            int tg = t0 + b2 * 32 + (r & 3) + 8 * (r >> 2) +
                                     4 * half;
                            if (tg > qg) v = -3.0e38f;
                            sa[b2][r] = v;
                            mx = fmaxf(mx, v);
                        }
                } else {
#pragma unroll
                    for (int b2 = 0; b2 < 2; b2++)
#pragma unroll
                        for (int r = 0; r < 16; r++) {
                            float v = sa[b2][r] * C2LOG;
                            sa[b2][r] = v;
                            mx = fmaxf(mx, v);
                        }
                }
                mx = fmaxf(mx, __shfl_xor(mx, 32, 64));

                // defer-max (T13): rescale only when max grew by >11 (log2)
                if (mx > mi + 11.0f) {
                    const float al = exp2_fast(mi - mx);
                    mi = mx;
                    li *= al;
#pragma unroll
                    for (int db = 0; db < 4; db++)
#pragma unroll
                        for (int r = 0; r < 16; r++) o[db][r] *= al;
                }

                // P = 2^(S-mi) in-place; row-sum
                float rs = 0.f;
#pragma unroll
                for (int b2 = 0; b2 < 2; b2++)
#pragma unroll
                    for (int r = 0; r < 16; r++) {
                        float pp = exp2_fast(sa[b2][r] - mi);
                        sa[b2][r] = pp;
                        rs += pp;
                    }
                rs += __shfl_xor(rs, 32, 64);
                li += rs;

                // in-register P -> PV B-operands (T12): per b2, 8 cvtpk pairs
                // + 4 permlane32_swap assemble bp[2b2], bp[2b2+1]
                // (t = kk*16 + half*8 + {0..7}) with no LDS round-trip.
                bf16x8 bp[4];
#pragma unroll
                for (int b2 = 0; b2 < 2; b2++) {
                    unsigned int w0 = cvtpk_bf16(sa[b2][0], sa[b2][1]);
                    unsigned int w1 = cvtpk_bf16(sa[b2][2], sa[b2][3]);
                    unsigned int w2 = cvtpk_bf16(sa[b2][4], sa[b2][5]);
                    unsigned int w3 = cvtpk_bf16(sa[b2][6], sa[b2][7]);
                    unsigned int w4 = cvtpk_bf16(sa[b2][8], sa[b2][9]);
                    unsigned int w5 = cvtpk_bf16(sa[b2][10], sa[b2][11]);
                    unsigned int w6 = cvtpk_bf16(sa[b2][12], sa[b2][13]);
                    unsigned int w7 = cvtpk_bf16(sa[b2][14], sa[b2][15]);
                    asm volatile("v_permlane32_swap_b32 %0, %1"
                                 : "+v"(w0), "+v"(w2));
                    asm volatile("v_permlane32_swap_b32 %0, %1"
                                 : "+v"(w1), "+v"(w3));
                    asm volatile("v_permlane32_swap_b32 %0, %1"
                                 : "+v"(w4), "+v"(w6));
                    asm volatile("v_permlane32_swap_b32 %0, %1"
                                 : "+v"(w5), "+v"(w7));
                    uint4 u0 = {w0, w1, w2, w3};
                    uint4 u1 = {w4, w5, w6, w7};
                    bp[2 * b2] = *reinterpret_cast<bf16x8*>(&u0);
                    bp[2 * b2 + 1] = *reinterpret_cast<bf16x8*>(&u1);
                }

                // O^T += Vt * P^T : 4 d-blocks, contraction t=64 (4 ksteps)
#pragma unroll
                for (int kk = 0; kk < 4; kk++) {
#pragma unroll
                    for (int db = 0; db < 4; db++) {
                        int row = db * 32 + l32;
                        bf16x8 av = *(const bf16x8*)(
                            Vtsc + row * 64 +
                            ((kk * 2 + half) ^ (row & 7)) * 8);
                        o[db] = __builtin_amdgcn_mfma_f32_32x32x16_bf16(
                            av, bp[kk], o[db], 0, 0, 0);
                    }
                }
            }
            cur ^= 1;
        }

        // epilogue: ctx[b, qg, h*128+d] = O^T[d][qg] / li (bf16, cvt_pk pairs)
        const float inv = 1.0f / li;
        unsigned short* dst = ctx + ((size_t)(b * Sd + qg)) * Ed + h * Dd;
#pragma unroll
        for (int db = 0; db < 4; db++)
#pragma unroll
            for (int g = 0; g < 4; g++) {
                uint2 w;
                w.x = cvtpk_bf16(o[db][g * 4 + 0] * inv,
                                 o[db][g * 4 + 1] * inv);
                w.y = cvtpk_bf16(o[db][g * 4 + 2] * inv,
                                 o[db][g * 4 + 3] * inv);
                *(uint2*)(dst + db * 32 + g * 8 + half * 4) = w;
            }
    }
}

extern "C" void kernel_launch(void* const* d_in, const int* in_sizes, int n_in,
                              void* d_out, int out_size, void* d_ws,
                              size_t ws_size, hipStream_t stream) {
    const float* x = (const float*)d_in[0];
    const float* wqkv_w = (const float*)d_in[1];
    const float* wqkv_b = (const float*)d_in[2];
    const float* out_w = (const float*)d_in[3];
    const float* out_b = (const float*)d_in[4];
    float* out = (float*)d_out;

    // workspace layout (bytes); total 100,663,296 (96 MiB)
    char* ws = (char*)d_ws;
    unsigned short* xb    = (unsigned short*)(ws + 0);         // 16 MiB, dead after QKV GEMM
    unsigned short* wqkvb = (unsigned short*)(ws + 16777216);  // 24 MiB
    unsigned short* owb   = (unsigned short*)(ws + 41943040);  // 8 MiB
    unsigned short* qb    = (unsigned short*)(ws + 50331648);  // 16 MiB [B,H,S,D]
    unsigned short* kb    = (unsigned short*)(ws + 67108864);  // 16 MiB [B,H,S,D]
    unsigned short* vtb   = (unsigned short*)(ws + 83886080);  // 16 MiB [B,H,D,S]
    unsigned short* ctx   = (unsigned short*)(ws + 0);         // alias xb (dead)

    cvt_all<<<12288, 256, 0, stream>>>(x, wqkv_w, out_w, xb, wqkvb, owb);
    // qkv = x @ wqkv_w^T + b, fused RoPE (q,k) + V-transpose in epilogue.
    // Single dispatch (measured 107-108 us at 4 blocks/CU; the R7-R9
    // two-half split ran at 3 blocks/CU + tail and served only diagnostics).
    gemm_bt<1><<<dim3(48, 32), 256, 0, stream>>>(xb, wqkvb, wqkv_b, qb, kb,
                                                 vtb, N3E, Ed, 0);
    // folded flash: 256 blocks (1/CU), each does qi=15-y then qi=y (34 iters)
    flash_attn<<<dim3(32, 8), 256, 0, stream>>>(qb, kb, vtb, ctx);
    // out = ctx @ out_w^T + b  (fp32)
    gemm_bt<0><<<dim3(16, 32), 256, 0, stream>>>(ctx, owb, out_b, out, nullptr,
                                                 nullptr, Ed, Ed, 0);
}

// Round 11
// 344.807 us; speedup vs baseline: 1.0285x; 1.0285x over previous
//
#include <hip/hip_runtime.h>
#include <cstdint>
#include <cstddef>

// Problem constants (B,S,E,H)=(2,2048,2048,16), D=128, RD=128 (full-rotary)
#define Bd 2
#define Sd 2048
#define Ed 2048
#define Hd 16
#define Dd 128
#define N3E 6144
#define ATT_SCALE 0.08838834764831845f   // 1/sqrt(128)
#define C2LOG 0.12751743f                // ATT_SCALE * log2(e): softmax in 2^x domain

typedef short bf16x8 __attribute__((ext_vector_type(8)));
typedef float f32x4 __attribute__((ext_vector_type(4)));
typedef float f32x16 __attribute__((ext_vector_type(16)));

__device__ __forceinline__ float bf2f(unsigned short u) {
    union { unsigned int u; float f; } c;
    c.u = ((unsigned int)u) << 16;
    return c.f;
}
__device__ __forceinline__ unsigned short f2bf(float f) {
    union { float f; unsigned int u; } c;
    c.f = f;
    unsigned int x = c.u;
    x += 0x7FFFu + ((x >> 16) & 1u);   // RTNE (finite values only)
    return (unsigned short)(x >> 16);
}

// raw v_exp_f32 = 2^x
__device__ __forceinline__ float exp2_fast(float x) {
    float r;
    asm("v_exp_f32 %0, %1" : "=v"(r) : "v"(x));
    return r;
}
// pack 2 f32 -> 2 bf16 (RTNE), lo in low half (T12 primitive; no builtin)
__device__ __forceinline__ unsigned int cvtpk_bf16(float lo, float hi) {
    unsigned int r;
    asm("v_cvt_pk_bf16_f32 %0, %1, %2" : "=v"(r) : "v"(lo), "v"(hi));
    return r;
}

__device__ __forceinline__ void gl2lds16(const void* g, void* l) {
    __builtin_amdgcn_global_load_lds(
        (const __attribute__((address_space(1))) void*)g,
        (__attribute__((address_space(3))) void*)l, 16, 0, 0);
}

// ---------------- fp32 -> bf16 convert (x, wqkv_w, out_w in one launch) ----
// (R11: reverted to the R0-R4 4-elem version -- the configuration that
//  produced the session-best 346.2 total; the 8-elem rewrite was never
//  verified as a win in isolation.)
__global__ void cvt_all(const float* __restrict__ x,
                        const float* __restrict__ w1,
                        const float* __restrict__ w2,
                        unsigned short* __restrict__ ox,
                        unsigned short* __restrict__ o1,
                        unsigned short* __restrict__ o2) {
    int i = (blockIdx.x * 256 + threadIdx.x) * 4;
    const float* s;
    unsigned short* d;
    int off;
    if (i < 8388608) { s = x; d = ox; off = i; }
    else if (i < 20971520) { s = w1; d = o1; off = i - 8388608; }
    else { s = w2; d = o2; off = i - 20971520; }
    const float4 v = *(const float4*)(s + off);
    d[off + 0] = f2bf(v.x);
    d[off + 1] = f2bf(v.y);
    d[off + 2] = f2bf(v.z);
    d[off + 3] = f2bf(v.w);
}

// ---------------- bf16 MFMA GEMM, C = A * B^T + bias ----------------
// (proven 927-TF structure: 128x128 tile, BK=64, 4 waves, 33 KB LDS ->
//  4 blocks/CU; inter-block overlap hides the per-tile drain.)
// A: M x K (K contig), Bm: N x K (K contig). XOR-swizzled LDS (8 chunks/row
// of 16B) so frag ds_read_b128 is 2-way (free).
// MODE 0: fp32 row-major out (o0), Ndim cols.
// MODE 1: fused QKV epilogue. Each 128-col tile = one head (D=128) of q/k/v:
//   tile -> LDS (bf16, stride 130), then q/k: RoPE + store [B,H,S,D];
//   v: transpose via column gather -> [B,H,D,S].
template <int MODE>
__global__ void gemm_bt(const unsigned short* __restrict__ A,
                        const unsigned short* __restrict__ Bm,
                        const float* __restrict__ bias,
                        void* __restrict__ o0, void* __restrict__ o1,
                        void* __restrict__ o2, int Ndim, int K) {
    // union: staging (As 16KB + Bs 16KB) / epilogue tile 128x130 bf16 (33,280B)
    __shared__ __align__(16) unsigned short U[16640];
    unsigned short* As = U;
    unsigned short* Bs = U + 8192;

    const int tid = threadIdx.x;
    const int lane = tid & 63;
    const int wave = tid >> 6;
    const int quad = lane >> 4;
    const int l16 = lane & 15;
    const int wr = wave >> 1;
    const int wc = wave & 1;

    const int n0 = blockIdx.x * 128;
    const int m0 = blockIdx.y * 128;

    const unsigned short* Ab = A + (size_t)m0 * K;
    const unsigned short* Bb = Bm + (size_t)n0 * K;

    const f32x4 fzero = {0.f, 0.f, 0.f, 0.f};
    f32x4 acc[4][4];
#pragma unroll
    for (int i = 0; i < 4; i++)
#pragma unroll
        for (int j = 0; j < 4; j++) acc[i][j] = fzero;

    for (int k0 = 0; k0 < K; k0 += 64) {
        __syncthreads();
#pragma unroll
        for (int it = 0; it < 4; ++it) {
            int L = it * 256 + tid;
            int row = L >> 3;
            int cs = L & 7;
            int gc = cs ^ (row & 7);
            gl2lds16(Ab + row * K + k0 + gc * 8, (void*)(As + L * 8));
            gl2lds16(Bb + row * K + k0 + gc * 8, (void*)(Bs + L * 8));
        }
        __syncthreads();
#pragma unroll
        for (int kk = 0; kk < 2; ++kk) {
            bf16x8 af[4], bfr[4];
#pragma unroll
            for (int i = 0; i < 4; i++) {
                int row = wr * 64 + i * 16 + l16;
                int cs = kk * 4 + quad;
                af[i] = *(const bf16x8*)(As + row * 64 + (cs ^ (row & 7)) * 8);
            }
#pragma unroll
            for (int j = 0; j < 4; j++) {
                int row = wc * 64 + j * 16 + l16;
                int cs = kk * 4 + quad;
                bfr[j] = *(const bf16x8*)(Bs + row * 64 + (cs ^ (row & 7)) * 8);
            }
#pragma unroll
            for (int i = 0; i < 4; i++)
#pragma unroll
                for (int j = 0; j < 4; j++)
                    acc[i][j] = __builtin_amdgcn_mfma_f32_16x16x32_bf16(
                        af[i], bfr[j], acc[i][j], 0, 0, 0);
        }
    }

    if (MODE == 0) {
#pragma unroll
        for (int j = 0; j < 4; j++) {
            int col = n0 + wc * 64 + j * 16 + l16;
            float bv = bias[col];
#pragma unroll
            for (int i = 0; i < 4; i++) {
                int rbase = m0 + wr * 64 + i * 16 + quad * 4;
#pragma unroll
                for (int r = 0; r < 4; r++)
                    ((float*)o0)[(size_t)(rbase + r) * Ndim + col] =
                        acc[i][j][r] + bv;
            }
        }
    } else {
        // ---- fused QKV epilogue ----
        __syncthreads();  // all frag reads of As/Bs done before tile overwrite
#pragma unroll
        for (int j = 0; j < 4; j++) {
            int coll = wc * 64 + j * 16 + l16;   // tile-local col = d
            float bv = bias[n0 + coll];
#pragma unroll
            for (int i = 0; i < 4; i++) {
                int rl = wr * 64 + i * 16 + quad * 4;
#pragma unroll
                for (int r = 0; r < 4; r++)
                    U[(rl + r) * 130 + coll] = f2bf(acc[i][j][r] + bv);
            }
        }
        __syncthreads();

        const int ch = n0 >> 7;         // 0..47
        const int c = ch >> 4;          // 0=q 1=k 2=v
        const int h = ch & 15;
        const int bb = m0 >> 11;        // batch (tile never crosses: 2048%128==0)
        const int s0 = m0 & 2047;

        if (c < 2) {
            unsigned short* dstq = (unsigned short*)(c == 0 ? o0 : o1);
            const size_t hb = ((size_t)(bb * Hd + h)) * Sd;
#pragma unroll
            for (int it = 0; it < 16; ++it) {
                int lin = it * 256 + tid;        // 128 rows x 32 d-pairs
                int row = lin >> 5, p = lin & 31;
                int s = s0 + row;
                unsigned int lo = *(const unsigned int*)(U + row * 130 + 2 * p);
                unsigned int hi =
                    *(const unsigned int*)(U + row * 130 + 64 + 2 * p);
                float v1a = bf2f((unsigned short)lo), v1b = bf2f(lo >> 16);
                float v2a = bf2f((unsigned short)hi), v2b = bf2f(hi >> 16);
                // theta_j = s * 10000^(-j/64),  j = 2p, 2p+1
                float fa = (float)s * __expf(-(float)(2 * p) *
                                             (9.210340371976184f / 64.0f));
                float fb = (float)s * __expf(-(float)(2 * p + 1) *
                                             (9.210340371976184f / 64.0f));
                float sna, csa, snb, csb;
                __sincosf(fa, &sna, &csa);
                __sincosf(fb, &snb, &csb);
                ushort2 r1, r2;
                r1.x = f2bf(v1a * csa - v2a * sna);
                r1.y = f2bf(v1b * csb - v2b * snb);
                r2.x = f2bf(v1a * sna + v2a * csa);
                r2.y = f2bf(v1b * snb + v2b * csb);
                unsigned short* dst = dstq + (hb + s) * Dd;
                *(ushort2*)(dst + 2 * p) = r1;
                *(ushort2*)(dst + 64 + 2 * p) = r2;
            }
        } else {
            unsigned short* dstv = (unsigned short*)o2;
            const size_t hb = ((size_t)(bb * Hd + h)) * Dd;
#pragma unroll
            for (int it = 0; it < 16; ++it) {
                int lin = it * 256 + tid;        // 128 d x 32 s-chunks
                int d = lin >> 5, sc = lin & 31;
                int s4 = sc * 4;
                ushort4 pk;
                pk.x = U[(s4 + 0) * 130 + d];
                pk.y = U[(s4 + 1) * 130 + d];
                pk.z = U[(s4 + 2) * 130 + d];
                pk.w = U[(s4 + 3) * 130 + d];
                *(ushort4*)(dstv + (hb + d) * Sd + s0 + s4) = pk;
            }
        }
    }
}

// ---------------- flash attention (causal, online softmax) ----------------
// R11: RESTORED R4 configuration (the session-best total, 346.2 us). Ledger
// reconstruction across R4-R10 (two hard anchors: QKV=108, flash_fold=74.4;
// residual cvt+out+overhead ~172 constant) puts THIS flash at ~65 us -- the
// best variant of the session. R5's "pairing is broken" diagnosis was wrong
// (its 14% occupancy came from R5's own single-buffer serialization); the
// R6-R9 rebuilds (equal pairing, in-reg P, fold) only reached 74.4.
// Structure: 32x32x16 MFMA, BM=128 (32 q/wave), BN=64. S^T = K*Q^T with Q in
// registers; O^T = Vt*P^T via Ps LDS round-trip. K/V double-buffered
// (LDS 80 KB, 2 blocks/CU), stage-early: ONE __syncthreads per tile, next
// tile's gl2lds issued right after it (drain hidden under compute).
// P rows are wave-private (no barrier before PV reads). VALU diet:
// log2-domain softmax (v_exp_f32 direct), mask only in diagonal-straddling
// tiles, defer-max (T13, THR=11 log2), cvt_pk packs, whole-tile skip above
// the diagonal.
// 32x32 layouts (verified m74/m101): A/B [n=lane&31][k=(lane>>5)*8+j];
// C/D col=lane&31, row=(reg&3)+8*(reg>>2)+4*(lane>>5).
__global__ __launch_bounds__(256, 2) void flash_attn(
    const unsigned short* __restrict__ q, const unsigned short* __restrict__ k,
    const unsigned short* __restrict__ vt, unsigned short* __restrict__ ctx) {
    __shared__ __align__(16) unsigned short Ks[2][64 * 128];   // 2x16 KB [t][d], 16 chunks/row, xor row&15
    __shared__ __align__(16) unsigned short Vts[2][128 * 64];  // 2x16 KB [d][t], 8 chunks/row, xor row&7
    __shared__ __align__(16) unsigned short Ps[128 * 64];      // 16 KB [q][t], 8 chunks/row, xor row&7

    const int tid = threadIdx.x;
    const int lane = tid & 63;
    const int wave = tid >> 6;
    const int l32 = lane & 31;
    const int half = lane >> 5;

    // qi pairing: CU gets blocks y and y+8 (round-robin, 512 blocks / 256 CU)
    // -> qi {15-y, y}: per-CU tile count constant (34).
    const int yy = blockIdx.y;
    const int qi = (yy < 8) ? 15 - yy : yy - 8;
    const int bh = blockIdx.x;
    const int q0 = qi * 128;
    const int qg = q0 + wave * 32 + l32;        // this lane's global q row
    const int prow = wave * 32 + l32;           // P row (q local)
    const int psw = prow & 7;                   // P swizzle key

    const unsigned short* kb = k + (size_t)bh * Sd * Dd;
    const unsigned short* vtb = vt + (size_t)bh * Dd * Sd;

    // Q fragments straight from global: lane owns row qg, frag ks covers
    // d = ks*16 + half*8 + {0..7}  (B-operand layout), 8 x 16B loads.
    bf16x8 aq[8];
    {
        const unsigned short* qrow = q + ((size_t)bh * Sd + qg) * Dd;
#pragma unroll
        for (int ks = 0; ks < 8; ks++)
            aq[ks] = *(const bf16x8*)(qrow + ks * 16 + half * 8);
    }

    f32x16 o[4];   // O^T: d-block db: row d = db*32+(r&3)+8*(r>>2)+4*half, col q=l32
#pragma unroll
    for (int db = 0; db < 4; db++)
#pragma unroll
        for (int r = 0; r < 16; r++) o[db][r] = 0.f;
    float mi = -3.0e38f, li = 0.f;

    // stage K [64t][128d] and Vt [128d][64t] into buffer b, 1024 16B-chunks each
    auto stage = [&](int b, int t0) {
#pragma unroll
        for (int it = 0; it < 4; ++it) {
            int L = it * 256 + tid;
            int rk = L >> 4;
            int ck = L & 15;
            int gk = ck ^ (rk & 15);
            gl2lds16(kb + (size_t)(t0 + rk) * Dd + gk * 8,
                     (void*)(&Ks[b][0] + L * 8));
            int rv = L >> 3;
            int cv = L & 7;
            int gv = cv ^ (rv & 7);
            gl2lds16(vtb + (size_t)rv * Sd + t0 + gv * 8,
                     (void*)(&Vts[b][0] + L * 8));
        }
    };

    const int tmax = q0 + 64;
    stage(0, 0);
    int cur = 0;
    for (int t0 = 0; t0 <= tmax; t0 += 64) {
        __syncthreads();   // buf[cur] landed; prev iter's buf[cur^1] reads done
        if (t0 + 64 <= tmax) stage(cur ^ 1, t0 + 64);

        // waves entirely above the diagonal have nothing to do this tile
        if (t0 <= q0 + wave * 32 + 31) {
            const unsigned short* Ksc = &Ks[cur][0];
            const unsigned short* Vtsc = &Vts[cur][0];

            // S^T = K * Q^T : 2 t-blocks of 32, contraction d=128 (8 ksteps)
            f32x16 sa[2];
#pragma unroll
            for (int b2 = 0; b2 < 2; b2++)
#pragma unroll
                for (int r = 0; r < 16; r++) sa[b2][r] = 0.f;
#pragma unroll
            for (int ks = 0; ks < 8; ks++) {
                int cd = ks * 2 + half;
#pragma unroll
                for (int b2 = 0; b2 < 2; b2++) {
                    int row = b2 * 32 + l32;
                    bf16x8 ak = *(const bf16x8*)(Ksc + row * 128 +
                                                 (cd ^ (row & 15)) * 8);
                    sa[b2] = __builtin_amdgcn_mfma_f32_32x32x16_bf16(
                        ak, aq[ks], sa[b2], 0, 0, 0);
                }
            }

            // scale into log2 domain; mask only if wave straddles diagonal
            float mx = -3.0e38f;
            if (t0 + 63 > q0 + wave * 32) {   // wave-uniform
#pragma unroll
                for (int b2 = 0; b2 < 2; b2++)
#pragma unroll
                    for (int r = 0; r < 16; r++) {
                        float v = sa[b2][r] * C2LOG;
                        int tg = t0 + b2 * 32 + (r & 3) + 8 * (r >> 2) + 4 * half;
                        if (tg > qg) v = -3.0e38f;
                        sa[b2][r] = v;
                        mx = fmaxf(mx, v);
                    }
            } else {
#pragma unroll
                for (int b2 = 0; b2 < 2; b2++)
#pragma unroll
                    for (int r = 0; r < 16; r++) {
                        float v = sa[b2][r] * C2LOG;
                        sa[b2][r] = v;
                        mx = fmaxf(mx, v);
                    }
            }
            mx = fmaxf(mx, __shfl_xor(mx, 32, 64));

            // defer-max (T13): rescale only when max grew by >11 (log2)
            if (mx > mi + 11.0f) {
                const float al = exp2_fast(mi - mx);
                mi = mx;
                li *= al;
#pragma unroll
                for (int db = 0; db < 4; db++)
#pragma unroll
                    for (int r = 0; r < 16; r++) o[db][r] *= al;
            }

            // P = 2^(S-mi), packed to bf16 via v_cvt_pk, row-sum alongside.
            // P store: row prow, chunk XOR-swizzled by prow&7; reg (b2,g) ->
            // t = b2*32+8g+4*half+{0..3} -> chunk b2*4+g, within-chunk half*4.
            // P rows are wave-private: no barrier before PV reads.
            float rs = 0.f;
#pragma unroll
            for (int b2 = 0; b2 < 2; b2++)
#pragma unroll
                for (int g = 0; g < 4; g++) {
                    float p0 = exp2_fast(sa[b2][g * 4 + 0] - mi);
                    float p1 = exp2_fast(sa[b2][g * 4 + 1] - mi);
                    float p2 = exp2_fast(sa[b2][g * 4 + 2] - mi);
                    float p3 = exp2_fast(sa[b2][g * 4 + 3] - mi);
                    rs += (p0 + p1) + (p2 + p3);
                    uint2 w;
                    w.x = cvtpk_bf16(p0, p1);
                    w.y = cvtpk_bf16(p2, p3);
                    *(uint2*)(Ps + prow * 64 + ((b2 * 4 + g) ^ psw) * 8 +
                              half * 4) = w;
                }
            rs += __shfl_xor(rs, 32, 64);
            li += rs;

            // O^T += Vt * P^T : 4 d-blocks, contraction t=64 (4 ksteps)
#pragma unroll
            for (int kk = 0; kk < 4; kk++) {
                bf16x8 bp = *(const bf16x8*)(Ps + prow * 64 +
                                             ((kk * 2 + half) ^ psw) * 8);
#pragma unroll
                for (int db = 0; db < 4; db++) {
                    int row = db * 32 + l32;
                    bf16x8 av = *(const bf16x8*)(
                        Vtsc + row * 64 + ((kk * 2 + half) ^ (row & 7)) * 8);
                    o[db] = __builtin_amdgcn_mfma_f32_32x32x16_bf16(
                        av, bp, o[db], 0, 0, 0);
                }
            }
        }
        cur ^= 1;
    }

    // epilogue: ctx[b, qg, h*128+d] = O^T[d][qg] / li  (bf16, cvt_pk pairs)
    const int b = bh >> 4;
    const int h = bh & 15;
    const float inv = 1.0f / li;
    unsigned short* dst = ctx + ((size_t)(b * Sd + qg)) * Ed + h * Dd;
#pragma unroll
    for (int db = 0; db < 4; db++)
#pragma unroll
        for (int g = 0; g < 4; g++) {
            uint2 w;
            w.x = cvtpk_bf16(o[db][g * 4 + 0] * inv, o[db][g * 4 + 1] * inv);
            w.y = cvtpk_bf16(o[db][g * 4 + 2] * inv, o[db][g * 4 + 3] * inv);
            *(uint2*)(dst + db * 32 + g * 8 + half * 4) = w;
        }
}

extern "C" void kernel_launch(void* const* d_in, const int* in_sizes, int n_in,
                              void* d_out, int out_size, void* d_ws,
                              size_t ws_size, hipStream_t stream) {
    const float* x = (const float*)d_in[0];
    const float* wqkv_w = (const float*)d_in[1];
    const float* wqkv_b = (const float*)d_in[2];
    const float* out_w = (const float*)d_in[3];
    const float* out_b = (const float*)d_in[4];
    float* out = (float*)d_out;

    // workspace layout (bytes); total 100,663,296 (96 MiB)
    char* ws = (char*)d_ws;
    unsigned short* xb    = (unsigned short*)(ws + 0);         // 16 MiB, dead after QKV GEMM
    unsigned short* wqkvb = (unsigned short*)(ws + 16777216);  // 24 MiB
    unsigned short* owb   = (unsigned short*)(ws + 41943040);  // 8 MiB
    unsigned short* qb    = (unsigned short*)(ws + 50331648);  // 16 MiB [B,H,S,D]
    unsigned short* kb    = (unsigned short*)(ws + 67108864);  // 16 MiB [B,H,S,D]
    unsigned short* vtb   = (unsigned short*)(ws + 83886080);  // 16 MiB [B,H,D,S]
    unsigned short* ctx   = (unsigned short*)(ws + 0);         // alias xb (dead)

    cvt_all<<<24576, 256, 0, stream>>>(x, wqkv_w, out_w, xb, wqkvb, owb);
    // qkv = x @ wqkv_w^T + b, fused RoPE (q,k) + V-transpose in epilogue
    gemm_bt<1><<<dim3(48, 32), 256, 0, stream>>>(xb, wqkvb, wqkv_b, qb, kb, vtb,
                                                 N3E, Ed);
    flash_attn<<<dim3(32, 16), 256, 0, stream>>>(qb, kb, vtb, ctx);
    // out = ctx @ out_w^T + b  (fp32)
    gemm_bt<0><<<dim3(16, 32), 256, 0, stream>>>(ctx, owb, out_b, out, nullptr,
                                                 nullptr, Ed, Ed);
}